// Round 3
// baseline (2347.975 us; speedup 1.0000x reference)
//
#include <hip/hip_runtime.h>
#include <hip/hip_bf16.h>

typedef unsigned short u16;
typedef short bf16x8 __attribute__((ext_vector_type(8)));   // 8 bf16 (4 VGPRs) MFMA frag
typedef float floatx4 __attribute__((ext_vector_type(4)));  // MFMA acc

#define B_DIM 2048
#define F_DIM 4096
#define H_DIM 1024
#define NSTEP 64

__device__ __forceinline__ float fast_tanh(float x) {
    // tanh(x) = 1 - 2/(e^{2x}+1); graceful at +-inf. Error << bf16 rounding.
    return 1.0f - 2.0f / (__expf(2.0f * x) + 1.0f);
}

__device__ __forceinline__ u16 f2b(float x) {  // fp32 -> bf16, round-to-nearest-even
    union { float f; unsigned u; } v; v.f = x;
    unsigned r = v.u + 0x7FFFu + ((v.u >> 16) & 1u);
    return (u16)(r >> 16);
}

// Load 8 contiguous elements as packed bf16 (int4). F32=1: read fp32 + convert RNE.
template<int F32>
__device__ __forceinline__ int4 ld8(const void* base, size_t elemOff) {
    if constexpr (F32) {
        const float* p = (const float*)base + elemOff;
        float4 lo = *(const float4*)p;
        float4 hi = *(const float4*)(p + 4);
        union { u16 h[8]; int4 v; } r;
        r.h[0] = f2b(lo.x); r.h[1] = f2b(lo.y); r.h[2] = f2b(lo.z); r.h[3] = f2b(lo.w);
        r.h[4] = f2b(hi.x); r.h[5] = f2b(hi.y); r.h[6] = f2b(hi.z); r.h[7] = f2b(hi.w);
        return r.v;
    } else {
        return *(const int4*)((const u16*)base + elemOff);
    }
}

// C = act(A @ W^T + bias1 + bias2 + pre)
// A: [M,K] row-major (fp32 if AF32 else bf16); W: [N,K] row-major (torch Linear layout).
// Tile: BM=128 x BN=64, BK=32; 256 threads = 4 waves, wave tile 64x32 (4x2 MFMA 16x16x32).
// Grid (N/64, M/128) = 256 blocks for M=2048,N=1024 -> one per CU.
// ACT: 0=none 1=relu 2=tanh. OUT_F32: fp32 out. ACTOR: fused hx@W_act^T partial-logit atomic.
template<int AF32, int WF32, int ACT, int OUT_F32, int HAS_PRE, int ACTOR>
__global__ __launch_bounds__(256)
void gemm_bt(const void* __restrict__ A, const void* __restrict__ W,
             const float* __restrict__ bias1, const float* __restrict__ bias2,
             const float* __restrict__ pre, void* __restrict__ Cout,
             const float* __restrict__ Wact, float* __restrict__ logits,
             const int N, const int K)
{
    constexpr int BM = 128, BN = 64, BK = 32, LS = 40; // +8 bf16 pad: 80B row stride -> 2-way bank alias = free
    __shared__ u16 As[2][BM * LS];
    __shared__ u16 Bs[2][BN * LS];

    const int tid  = threadIdx.x;
    const int wave = tid >> 6, lane = tid & 63;
    const int wm = wave >> 1, wn = wave & 1;
    const int r = lane & 15, q = lane >> 4;
    const int m0 = blockIdx.y * BM, n0 = blockIdx.x * BN;

    floatx4 acc[4][2];
    const floatx4 zf = {0.f, 0.f, 0.f, 0.f};
    #pragma unroll
    for (int a = 0; a < 4; a++)
        #pragma unroll
        for (int b = 0; b < 2; b++) acc[a][b] = zf;

    // Staging: 8-elem chunks. A tile 128x32 (2 chunks/thread), B tile 64x32 (1 chunk/thread).
    const int row0 = tid >> 2;             // 0..63
    const int kc   = (tid & 3) << 3;       // k offset in elements (0,8,16,24)
    const int row1 = row0 + 64;            // A rows 64..127
    const size_t aOff0 = (size_t)(m0 + row0) * K + kc;
    const size_t aOff1 = (size_t)(m0 + row1) * K + kc;
    const size_t wOff  = (size_t)(n0 + row0) * K + kc;

    int4 av0 = ld8<AF32>(A, aOff0);
    int4 av1 = ld8<AF32>(A, aOff1);
    int4 bv  = ld8<WF32>(W, wOff);

    int p = 0;
    for (int kb = 0; kb < K; kb += BK) {
        *(int4*)&As[p][row0 * LS + kc] = av0;
        *(int4*)&As[p][row1 * LS + kc] = av1;
        *(int4*)&Bs[p][row0 * LS + kc] = bv;
        __syncthreads();  // lgkmcnt drained before s_barrier -> buffer reuse 2 iters later is safe
        if (kb + BK < K) {  // prefetch next K-slice; latency hidden behind MFMAs
            av0 = ld8<AF32>(A, aOff0 + kb + BK);
            av1 = ld8<AF32>(A, aOff1 + kb + BK);
            bv  = ld8<WF32>(W, wOff + kb + BK);
        }
        bf16x8 af[4], bq[2];
        #pragma unroll
        for (int t = 0; t < 4; t++)  // A frag: lane holds A[m=r][k=q*8..q*8+7]
            af[t] = *(const bf16x8*)&As[p][(wm * 64 + t * 16 + r) * LS + q * 8];
        #pragma unroll
        for (int t = 0; t < 2; t++)  // B frag: lane holds W[n=r][k=q*8..]
            bq[t] = *(const bf16x8*)&Bs[p][(wn * 32 + t * 16 + r) * LS + q * 8];
        #pragma unroll
        for (int mt = 0; mt < 4; mt++)
            #pragma unroll
            for (int nt = 0; nt < 2; nt++)
                acc[mt][nt] = __builtin_amdgcn_mfma_f32_16x16x32_bf16(af[mt], bq[nt], acc[mt][nt], 0, 0, 0);
        p ^= 1;
    }

    // Epilogue. C/D layout: row = q*4+i, col = r (m89/m91-verified).
    float biasv[2], wa[2];
    #pragma unroll
    for (int nt = 0; nt < 2; nt++) {
        const int col = n0 + wn * 32 + nt * 16 + r;
        float b = 0.f;
        if (bias1) b += bias1[col];
        if (bias2) b += bias2[col];
        biasv[nt] = b;
        if (ACTOR) wa[nt] = Wact[col];
    }
    #pragma unroll
    for (int mt = 0; mt < 4; mt++) {
        #pragma unroll
        for (int nt = 0; nt < 2; nt++) {
            const int col  = n0 + wn * 32 + nt * 16 + r;
            const int rowb = m0 + wm * 64 + mt * 16 + q * 4;
            #pragma unroll
            for (int i = 0; i < 4; i++) {
                float v = acc[mt][nt][i] + biasv[nt];
                if (HAS_PRE) v += pre[(size_t)(rowb + i) * N + col];
                if (ACT == 1) v = fmaxf(v, 0.f);
                if (ACT == 2) v = fast_tanh(v);
                if (OUT_F32) ((float*)Cout)[(size_t)(rowb + i) * N + col] = v;
                else ((u16*)Cout)[(size_t)(rowb + i) * N + col] = f2b(v);
                acc[mt][nt][i] = v;  // keep activated value for the actor pass
            }
        }
    }
    if (ACTOR) {
        // partial actor logit: sum over this wave's 32 cols, reduce across r (16 lanes of a quad)
        #pragma unroll
        for (int mt = 0; mt < 4; mt++) {
            #pragma unroll
            for (int i = 0; i < 4; i++) {
                float s = acc[mt][0][i] * wa[0] + acc[mt][1][i] * wa[1];
                s += __shfl_xor(s, 1);
                s += __shfl_xor(s, 2);
                s += __shfl_xor(s, 4);
                s += __shfl_xor(s, 8);
                if (r == 0) atomicAdd(&logits[m0 + wm * 64 + mt * 16 + q * 4 + i], s);
            }
        }
    }
}

// Wsum = bf16(W_ih + W_hh), Whhb = bf16(W_hh)  (one pass over both fp32 weights)
__global__ void prep_w(const float* __restrict__ Wih, const float* __restrict__ Whh,
                       u16* __restrict__ Wsum, u16* __restrict__ Whhb, int n) {
    int i = blockIdx.x * 256 + threadIdx.x;
    if (i < n) {
        float a = Wih[i], b = Whh[i];
        Wsum[i] = f2b(a + b);
        Whhb[i] = f2b(b);
    }
}

__global__ void sigmoid_kernel(const float* __restrict__ logits, const float* __restrict__ b_act,
                               float* __restrict__ out, int n) {
    int i = blockIdx.x * 256 + threadIdx.x;
    if (i < n) {
        float z = logits[i] + b_act[0];
        out[i] = 1.0f / (1.0f + __expf(-z));
    }
}

extern "C" void kernel_launch(void* const* d_in, const int* in_sizes, int n_in,
                              void* d_out, int out_size, void* d_ws, size_t ws_size,
                              hipStream_t stream) {
    (void)in_sizes; (void)n_in; (void)out_size; (void)ws_size;
    const int Bn = B_DIM, F = F_DIM, H = H_DIM;

    const float* xin[3] = {(const float*)d_in[0], (const float*)d_in[1], (const float*)d_in[2]};
    const float* W1[3]  = {(const float*)d_in[3], (const float*)d_in[7], (const float*)d_in[11]};
    const float* b1[3]  = {(const float*)d_in[4], (const float*)d_in[8], (const float*)d_in[12]};
    const float* W2[3]  = {(const float*)d_in[5], (const float*)d_in[9], (const float*)d_in[13]};
    const float* b2[3]  = {(const float*)d_in[6], (const float*)d_in[10], (const float*)d_in[14]};
    const float* W_ih   = (const float*)d_in[15];
    const float* W_hh   = (const float*)d_in[16];
    const float* b_ih   = (const float*)d_in[17];
    const float* b_hh   = (const float*)d_in[18];
    const float* W_act  = (const float*)d_in[19];
    const float* b_act  = (const float*)d_in[20];

    // workspace layout (48.5 MB total)
    const size_t MB = 1024 * 1024;
    char* ws = (char*)d_ws;
    u16*   xl     = (u16*)(ws + 0 * MB);    // [2048,1024] bf16 MLP outputs
    u16*   xm     = (u16*)(ws + 4 * MB);
    u16*   xh     = (u16*)(ws + 8 * MB);    // also hx ping buffer
    u16*   hxB    = (u16*)(ws + 12 * MB);   // hx pong buffer
    u16*   h1     = (u16*)(ws + 16 * MB);   // MLP intermediate (reused x3)
    u16*   Wsum   = (u16*)(ws + 20 * MB);   // bf16(W_ih + W_hh), [1024,1024]
    u16*   Whhb   = (u16*)(ws + 22 * MB);   // bf16(W_hh)
    float* pre_xh = (float*)(ws + 24 * MB); // [2048,1024] fp32
    float* pre_xm = (float*)(ws + 32 * MB);
    float* pre_xl = (float*)(ws + 40 * MB);
    float* logits = (float*)(ws + 48 * MB); // [64,2048] fp32

    dim3 grid(H / 64, Bn / 128);  // (16,16) = 256 blocks
    dim3 blk(256);

    (void)hipMemsetAsync(logits, 0, (size_t)NSTEP * Bn * sizeof(float), stream);
    prep_w<<<dim3((H * H + 255) / 256), blk, 0, stream>>>(W_ih, W_hh, Wsum, Whhb, H * H);

    // MLPs: x' = relu(relu(x@W1^T + b1)@W2^T + b2)   -> xl, xm, xh (bf16)
    u16* xout[3] = {xl, xm, xh};
    for (int m = 0; m < 3; m++) {
        gemm_bt<1,1,1,0,0,0><<<grid, blk, 0, stream>>>(xin[m], W1[m], b1[m], nullptr, nullptr,
                                                       h1, nullptr, nullptr, H, F);
        gemm_bt<0,1,1,0,0,0><<<grid, blk, 0, stream>>>(h1, W2[m], b2[m], nullptr, nullptr,
                                                       xout[m], nullptr, nullptr, H, H);
    }
    // pre = ipt @ W_ih^T + b_ih (fp32), hoisted out of the sequential chain
    gemm_bt<0,1,0,1,0,0><<<grid, blk, 0, stream>>>(xh, W_ih, b_ih, nullptr, nullptr,
                                                   pre_xh, nullptr, nullptr, H, H);
    gemm_bt<0,1,0,1,0,0><<<grid, blk, 0, stream>>>(xm, W_ih, b_ih, nullptr, nullptr,
                                                   pre_xm, nullptr, nullptr, H, H);
    gemm_bt<0,1,0,1,0,0><<<grid, blk, 0, stream>>>(xl, W_ih, b_ih, nullptr, nullptr,
                                                   pre_xl, nullptr, nullptr, H, H);

    // sequential RNN: static branch trace -> special steps {15:xh, 21:xm, 37:xm, 42:xl, 58:xl}
    u16* hx = xh;
    u16* nxt = hxB;
    for (int step = 0; step < NSTEP; step++) {
        const float* pre = nullptr;
        if (step == 15) pre = pre_xh;
        else if (step == 21 || step == 37) pre = pre_xm;
        else if (step == 42 || step == 58) pre = pre_xl;
        float* lg = logits + (size_t)step * Bn;
        if (step == NSTEP - 1) {
            // final step: fp32 hx straight into d_out (after the probs block)
            float* outf = (float*)d_out + (size_t)NSTEP * Bn;
            gemm_bt<0,0,2,1,0,1><<<grid, blk, 0, stream>>>(hx, Wsum, b_ih, b_hh, nullptr,
                                                           outf, W_act, lg, H, H);
        } else if (pre) {  // hx' = tanh(hx@W_hh^T + b_hh + pre)
            gemm_bt<0,0,2,0,1,1><<<grid, blk, 0, stream>>>(hx, Whhb, nullptr, b_hh, pre,
                                                           nxt, W_act, lg, H, H);
        } else {           // hx' = tanh(hx@(W_ih+W_hh)^T + b_ih + b_hh)
            gemm_bt<0,0,2,0,0,1><<<grid, blk, 0, stream>>>(hx, Wsum, b_ih, b_hh, nullptr,
                                                           nxt, W_act, lg, H, H);
        }
        u16* t = hx; hx = nxt; nxt = t;
    }
    // probs[step][b] = sigmoid(logit + b_act)
    sigmoid_kernel<<<dim3((NSTEP * Bn + 255) / 256), blk, 0, stream>>>(logits, b_act,
                                                                      (float*)d_out, NSTEP * Bn);
}

// Round 4
// 1543.286 us; speedup vs baseline: 1.5214x; 1.5214x over previous
//
#include <hip/hip_runtime.h>
#include <hip/hip_bf16.h>

typedef unsigned short u16;
typedef short bf16x8 __attribute__((ext_vector_type(8)));   // 8 bf16 (4 VGPRs) MFMA frag
typedef float floatx4 __attribute__((ext_vector_type(4)));  // MFMA acc

#define B_DIM 2048
#define F_DIM 4096
#define H_DIM 1024
#define NSTEP 64

__device__ __forceinline__ float fast_tanh(float x) {
    return 1.0f - 2.0f / (__expf(2.0f * x) + 1.0f);
}

__device__ __forceinline__ u16 f2b(float x) {  // fp32 -> bf16 RNE
    union { float f; unsigned u; } v; v.f = x;
    unsigned r = v.u + 0x7FFFu + ((v.u >> 16) & 1u);
    return (u16)(r >> 16);
}

// Load 8 contiguous elements as packed bf16 (int4). F32=1: read fp32 + convert RNE.
template<int F32>
__device__ __forceinline__ int4 ld8(const void* base, size_t elemOff) {
    if constexpr (F32) {
        const float* p = (const float*)base + elemOff;
        float4 lo = *(const float4*)p;
        float4 hi = *(const float4*)(p + 4);
        union { u16 h[8]; int4 v; } rr;
        rr.h[0] = f2b(lo.x); rr.h[1] = f2b(lo.y); rr.h[2] = f2b(lo.z); rr.h[3] = f2b(lo.w);
        rr.h[4] = f2b(hi.x); rr.h[5] = f2b(hi.y); rr.h[6] = f2b(hi.z); rr.h[7] = f2b(hi.w);
        return rr.v;
    } else {
        return *(const int4*)((const u16*)base + elemOff);
    }
}

// C[z] = act(A[z] @ W[z]^T + bias1[z] + bias2 + pre)
// BM=64 x BN=64, BK=64. 256 threads = 4 waves (2x2), wave tile 32x32 (2x2 MFMA 16x16x32).
// Grid MUST be (16, 32, z): N=1024, M=2048. 512 blocks/slice = 2 blocks/CU (8 waves/CU).
// XCD swizzle: lin%8 == m-tile%8 -> A row-panels (and the next step's hx writes) pinned per XCD L2.
// ACT: 0=none 1=relu 2=tanh. OUT_F32: fp32 C. ACTOR: fused hx@W_act^T partial-logit atomic.
template<int AF32, int WF32, int ACT, int OUT_F32, int HAS_PRE, int ACTOR>
__global__ __launch_bounds__(256)
void gemm64(const void* __restrict__ A0, const void* __restrict__ A1, const void* __restrict__ A2,
            const void* __restrict__ Wp0, const void* __restrict__ Wp1, const void* __restrict__ Wp2,
            const float* __restrict__ bia0, const float* __restrict__ bia1, const float* __restrict__ bia2,
            const float* __restrict__ bias2p, const float* __restrict__ pre,
            void* __restrict__ C0, void* __restrict__ C1, void* __restrict__ C2,
            const float* __restrict__ Wact, float* __restrict__ logits,
            const int N, const int K)
{
    constexpr int BM = 64, BN = 64, BK = 64, LS = 72; // 144B row stride = 36 banks -> 2-way alias (free)
    __shared__ u16 As[2][BM * LS];  // 18 KB
    __shared__ u16 Bs[2][BN * LS];  // 18 KB  (36.9 KB total -> 4 blocks/CU LDS-max)

    const int z = blockIdx.z;
    const void*  A     = (z == 0) ? A0 : (z == 1) ? A1 : A2;
    const void*  W     = (z == 0) ? Wp0 : (z == 1) ? Wp1 : Wp2;
    const float* bias1 = (z == 0) ? bia0 : (z == 1) ? bia1 : bia2;
    void*        Cout  = (z == 0) ? C0 : (z == 1) ? C1 : C2;

    const int tid  = threadIdx.x;
    const int wave = tid >> 6, lane = tid & 63;
    const int wm = wave >> 1, wn = wave & 1;
    const int r = lane & 15, q = lane >> 4;

    // swizzle: 512 blocks/slice; lin%8 (XCD heuristic) == m-tile%8
    const int lin = blockIdx.y * 16 + blockIdx.x;
    const int mti = (lin & 7) | ((lin >> 7) << 3);   // 0..31
    const int nti = (lin >> 3) & 15;                 // 0..15
    const int m0 = mti * BM, n0 = nti * BN;

    floatx4 acc[2][2];
    const floatx4 zf = {0.f, 0.f, 0.f, 0.f};
    #pragma unroll
    for (int a = 0; a < 2; a++)
        #pragma unroll
        for (int b = 0; b < 2; b++) acc[a][b] = zf;

    // Staging: tiles 64x64 = 512 8-elem chunks; 2 A-chunks + 2 B-chunks per thread.
    const int row0 = tid >> 3;            // 0..31
    const int kc   = (tid & 7) << 3;      // 0..56
    const int row1 = row0 + 32;
    const size_t aOff0 = (size_t)(m0 + row0) * K + kc;
    const size_t aOff1 = (size_t)(m0 + row1) * K + kc;
    const size_t wOff0 = (size_t)(n0 + row0) * K + kc;
    const size_t wOff1 = (size_t)(n0 + row1) * K + kc;

    int4 av0 = ld8<AF32>(A, aOff0);
    int4 av1 = ld8<AF32>(A, aOff1);
    int4 bv0 = ld8<WF32>(W, wOff0);
    int4 bv1 = ld8<WF32>(W, wOff1);

    int p = 0;
    for (int kb = 0; kb < K; kb += BK) {
        *(int4*)&As[p][row0 * LS + kc] = av0;
        *(int4*)&As[p][row1 * LS + kc] = av1;
        *(int4*)&Bs[p][row0 * LS + kc] = bv0;
        *(int4*)&Bs[p][row1 * LS + kc] = bv1;
        __syncthreads();
        if (kb + BK < K) {
            av0 = ld8<AF32>(A, aOff0 + kb + BK);
            av1 = ld8<AF32>(A, aOff1 + kb + BK);
            bv0 = ld8<WF32>(W, wOff0 + kb + BK);
            bv1 = ld8<WF32>(W, wOff1 + kb + BK);
        }
        bf16x8 af[2][2], bf[2][2];
        #pragma unroll
        for (int ks = 0; ks < 2; ks++) {
            #pragma unroll
            for (int t = 0; t < 2; t++) {
                af[ks][t] = *(const bf16x8*)&As[p][(wm * 32 + t * 16 + r) * LS + ks * 32 + q * 8];
                bf[ks][t] = *(const bf16x8*)&Bs[p][(wn * 32 + t * 16 + r) * LS + ks * 32 + q * 8];
            }
        }
        #pragma unroll
        for (int ks = 0; ks < 2; ks++)
            #pragma unroll
            for (int mt = 0; mt < 2; mt++)
                #pragma unroll
                for (int nt = 0; nt < 2; nt++)
                    acc[mt][nt] = __builtin_amdgcn_mfma_f32_16x16x32_bf16(af[ks][mt], bf[ks][nt], acc[mt][nt], 0, 0, 0);
        p ^= 1;
    }

    // Epilogue. C/D layout: row = q*4+i, col = r (m89/m91-verified).
    float biasv[2], wa[2];
    #pragma unroll
    for (int nt = 0; nt < 2; nt++) {
        const int col = n0 + wn * 32 + nt * 16 + r;
        float b = 0.f;
        if (bias1)  b += bias1[col];
        if (bias2p) b += bias2p[col];
        biasv[nt] = b;
        if (ACTOR) wa[nt] = Wact[col];
    }
    #pragma unroll
    for (int mt = 0; mt < 2; mt++) {
        #pragma unroll
        for (int nt = 0; nt < 2; nt++) {
            const int col  = n0 + wn * 32 + nt * 16 + r;
            const int rowb = m0 + wm * 32 + mt * 16 + q * 4;
            #pragma unroll
            for (int i = 0; i < 4; i++) {
                float v = acc[mt][nt][i] + biasv[nt];
                if (HAS_PRE) v += pre[(size_t)(rowb + i) * N + col];
                if (ACT == 1) v = fmaxf(v, 0.f);
                if (ACT == 2) v = fast_tanh(v);
                if (OUT_F32) ((float*)Cout)[(size_t)(rowb + i) * N + col] = v;
                else ((u16*)Cout)[(size_t)(rowb + i) * N + col] = f2b(v);
                acc[mt][nt][i] = v;
            }
        }
    }
    if (ACTOR) {
        #pragma unroll
        for (int mt = 0; mt < 2; mt++) {
            #pragma unroll
            for (int i = 0; i < 4; i++) {
                float s = acc[mt][0][i] * wa[0] + acc[mt][1][i] * wa[1];
                s += __shfl_xor(s, 1);
                s += __shfl_xor(s, 2);
                s += __shfl_xor(s, 4);
                s += __shfl_xor(s, 8);
                if (r == 0) atomicAdd(&logits[m0 + wm * 32 + mt * 16 + q * 4 + i], s);
            }
        }
    }
}

// Wsum = bf16(W_ih+W_hh), Whhb = bf16(W_hh), Wihb = bf16(W_ih)
__global__ void prep_w(const float* __restrict__ Wih, const float* __restrict__ Whh,
                       u16* __restrict__ Wsum, u16* __restrict__ Whhb, u16* __restrict__ Wihb, int n) {
    int i = blockIdx.x * 256 + threadIdx.x;
    if (i < n) {
        float a = Wih[i], b = Whh[i];
        Wsum[i] = f2b(a + b);
        Whhb[i] = f2b(b);
        Wihb[i] = f2b(a);
    }
}

__global__ void sigmoid_kernel(const float* __restrict__ logits, const float* __restrict__ b_act,
                               float* __restrict__ out, int n) {
    int i = blockIdx.x * 256 + threadIdx.x;
    if (i < n) {
        float zv = logits[i] + b_act[0];
        out[i] = 1.0f / (1.0f + __expf(-zv));
    }
}

extern "C" void kernel_launch(void* const* d_in, const int* in_sizes, int n_in,
                              void* d_out, int out_size, void* d_ws, size_t ws_size,
                              hipStream_t stream) {
    (void)in_sizes; (void)n_in; (void)out_size; (void)ws_size;
    const int Bn = B_DIM, F = F_DIM, H = H_DIM;

    const float* xin[3] = {(const float*)d_in[0], (const float*)d_in[1], (const float*)d_in[2]};
    const float* W1[3]  = {(const float*)d_in[3], (const float*)d_in[7], (const float*)d_in[11]};
    const float* b1[3]  = {(const float*)d_in[4], (const float*)d_in[8], (const float*)d_in[12]};
    const float* W2[3]  = {(const float*)d_in[5], (const float*)d_in[9], (const float*)d_in[13]};
    const float* b2[3]  = {(const float*)d_in[6], (const float*)d_in[10], (const float*)d_in[14]};
    const float* W_ih   = (const float*)d_in[15];
    const float* W_hh   = (const float*)d_in[16];
    const float* b_ih   = (const float*)d_in[17];
    const float* b_hh   = (const float*)d_in[18];
    const float* W_act  = (const float*)d_in[19];
    const float* b_act  = (const float*)d_in[20];

    // workspace layout (46.5 MB; h1 buffers overlap the later pre_* region — h1 dead before pre is written)
    const size_t MB = 1024 * 1024;
    char* ws = (char*)d_ws;
    u16*   xl     = (u16*)(ws + 0 * MB);
    u16*   xm     = (u16*)(ws + 4 * MB);
    u16*   xh     = (u16*)(ws + 8 * MB);    // hx ping
    u16*   hxB    = (u16*)(ws + 12 * MB);   // hx pong
    u16*   Wsum   = (u16*)(ws + 16 * MB);
    u16*   Whhb   = (u16*)(ws + 18 * MB);
    u16*   Wihb   = (u16*)(ws + 20 * MB);
    u16*   h1a    = (u16*)(ws + 22 * MB);   // 4 MB each, overlap pre region
    u16*   h1b    = (u16*)(ws + 26 * MB);
    u16*   h1c    = (u16*)(ws + 30 * MB);
    float* pre_xh = (float*)(ws + 22 * MB); // 8 MB each, written after fc2 consumed h1
    float* pre_xm = (float*)(ws + 30 * MB);
    float* pre_xl = (float*)(ws + 38 * MB);
    float* logits = (float*)(ws + 46 * MB); // 512 KB

    dim3 gridH(16, 32, 1);   // N/64=16, M/64=32 (swizzle assumes exactly this)
    dim3 grid3(16, 32, 3);
    dim3 blk(256);

    (void)hipMemsetAsync(logits, 0, (size_t)NSTEP * Bn * sizeof(float), stream);
    prep_w<<<dim3((H * H + 255) / 256), blk, 0, stream>>>(W_ih, W_hh, Wsum, Whhb, Wihb, H * H);

    // fc1 (batched z=3): h1[z] = relu(x[z] @ W1[z]^T + b1[z])
    gemm64<1,1,1,0,0,0><<<grid3, blk, 0, stream>>>(
        xin[0], xin[1], xin[2], W1[0], W1[1], W1[2], b1[0], b1[1], b1[2],
        nullptr, nullptr, h1a, h1b, h1c, nullptr, nullptr, H, F);
    // fc2 (batched): xout[z] = relu(h1[z] @ W2[z]^T + b2[z])
    gemm64<0,1,1,0,0,0><<<grid3, blk, 0, stream>>>(
        h1a, h1b, h1c, W2[0], W2[1], W2[2], b2[0], b2[1], b2[2],
        nullptr, nullptr, xl, xm, xh, nullptr, nullptr, H, H);
    // pre (batched): pre_* = {xh,xm,xl} @ W_ih^T + b_ih (fp32)
    gemm64<0,0,0,1,0,0><<<grid3, blk, 0, stream>>>(
        xh, xm, xl, Wihb, Wihb, Wihb, b_ih, b_ih, b_ih,
        nullptr, nullptr, pre_xh, pre_xm, pre_xl, nullptr, nullptr, H, H);

    // sequential RNN: special steps {15:xh, 21:xm, 37:xm, 42:xl, 58:xl}
    u16* hx = xh;
    u16* nxt = hxB;
    for (int step = 0; step < NSTEP; step++) {
        const float* pre = nullptr;
        if (step == 15) pre = pre_xh;
        else if (step == 21 || step == 37) pre = pre_xm;
        else if (step == 42 || step == 58) pre = pre_xl;
        float* lg = logits + (size_t)step * Bn;
        if (step == NSTEP - 1) {
            float* outf = (float*)d_out + (size_t)NSTEP * Bn;
            gemm64<0,0,2,1,0,1><<<gridH, blk, 0, stream>>>(
                hx, hx, hx, Wsum, Wsum, Wsum, b_ih, b_ih, b_ih,
                b_hh, nullptr, outf, outf, outf, W_act, lg, H, H);
        } else if (pre) {
            gemm64<0,0,2,0,1,1><<<gridH, blk, 0, stream>>>(
                hx, hx, hx, Whhb, Whhb, Whhb, nullptr, nullptr, nullptr,
                b_hh, pre, nxt, nxt, nxt, W_act, lg, H, H);
        } else {
            gemm64<0,0,2,0,0,1><<<gridH, blk, 0, stream>>>(
                hx, hx, hx, Wsum, Wsum, Wsum, b_ih, b_ih, b_ih,
                b_hh, nullptr, nxt, nxt, nxt, W_act, lg, H, H);
        }
        u16* t = hx; hx = nxt; nxt = t;
    }
    sigmoid_kernel<<<dim3((NSTEP * Bn + 255) / 256), blk, 0, stream>>>(logits, b_act,
                                                                      (float*)d_out, NSTEP * Bn);
}